// Round 4
// baseline (654.523 us; speedup 1.0000x reference)
//
#include <hip/hip_runtime.h>
#include <stdint.h>

// InstanceSampling: greedy per-class radius suppression (exact reference semantics).
// B=2, N=8192, C=3, L=16384. RADII = {0.5,0.6,0.7}; radius of pick #i is
// RADII[label of sorted slot i] (reference quirk: indexed by pick ORDINAL).
//
// k1 init+keys -> k2 O(L^2) rank sort -> g2 scan -> g3 cell scatter ->
// k3 greedy (single block; FIXED 128-wide sorted-position windows, register-
// prefetched; wave0 resolves window t while waves 1..15 apply suppression of
// batch t-1; aliveness = rem bit + patch vs the one in-flight batch) -> k4 out.

#define L_TOT 16384
#define NPT   8192

__device__ __forceinline__ int cellco(float v) {
    int c = (int)floorf((v + 6.4f) * 1.25f);   // cell size 0.8 >= max radius 0.7
    return c < 0 ? 0 : (c > 15 ? 15 : c);
}
__device__ __forceinline__ float d2f(float ax, float ay, float az,
                                     float bx, float by, float bz) {
    float dx = __fsub_rn(ax, bx), dy = __fsub_rn(ay, by), dz = __fsub_rn(az, bz);
    return __fadd_rn(__fadd_rn(__fmul_rn(dx, dx), __fmul_rn(dy, dy)), __fmul_rn(dz, dz));
}
__device__ __forceinline__ float rad2(int lb) {
    float rr = (lb == 0) ? 0.5f : ((lb == 1) ? 0.6f : 0.7f);
    return __fmul_rn(rr, rr);
}

// ---------------- k1: init + per-point keys ----------------
__global__ void k1_keys(const float* __restrict__ cls, uint64_t* __restrict__ keys,
                        uint8_t* __restrict__ umeta, uint16_t* __restrict__ sample,
                        int* __restrict__ cellcnt) {
    int l = blockIdx.x * blockDim.x + threadIdx.x;
    if (l >= L_TOT) return;
    ((uint32_t*)sample)[l] = 0;                  // zero 2*L u16
    if (l < 8192) cellcnt[l] = 0;
    float c0 = cls[l * 3 + 0], c1 = cls[l * 3 + 1], c2 = cls[l * 3 + 2];
    float m = c0; int lab = 0;
    if (c1 > m) { m = c1; lab = 1; }   // strict > : first-max, matches jnp.argmax
    if (c2 > m) { m = c2; lab = 2; }
    int valid = (m >= 0.0f) ? 1 : 0;   // sigmoid(m) >= 0.5  <=>  m >= 0
    float keyf = valid ? m : -__builtin_inff();
    uint32_t u = __float_as_uint(keyf);
    uint32_t o = (u & 0x80000000u) ? ~u : (u | 0x80000000u); // order-preserving map
    keys[l] = ((uint64_t)(~o) << 32) | (uint32_t)l;          // asc == desc score, stable
    umeta[l] = (uint8_t)(lab | (valid << 2));
}

// ---------------- k2: O(L^2) rank sort + build sorted arrays + cell counts ----
__global__ void __launch_bounds__(256) k2_sort(
    const uint64_t* __restrict__ keys, const uint8_t* __restrict__ umeta,
    const float* __restrict__ xyz,
    float4* __restrict__ spts, uint8_t* __restrict__ slab, uint16_t* __restrict__ sorder,
    int* __restrict__ cellcnt) {
    __shared__ uint64_t tile[2048];
    __shared__ int psum[256];
    const int t = threadIdx.x;
    const int elem = t & 31, part = t >> 5;
    const int l = blockIdx.x * 32 + elem;
    const uint64_t myk = keys[l];
    int cnt = 0;
    for (int t0 = 0; t0 < L_TOT; t0 += 2048) {
        for (int j = t; j < 2048; j += 256) tile[j] = keys[t0 + j];
        __syncthreads();
        const int b0 = part * 256;
        #pragma unroll 4
        for (int j = 0; j < 256; ++j) cnt += (tile[b0 + j] < myk) ? 1 : 0;
        __syncthreads();
    }
    psum[t] = cnt;
    __syncthreads();
    if (t < 32) {
        int rank = 0;
        #pragma unroll
        for (int q = 0; q < 8; ++q) rank += psum[q * 32 + t];
        const int ll = blockIdx.x * 32 + t;
        int b = ll >> 13, p = ll & (NPT - 1);
        const float* src = xyz + ((size_t)(b * NPT + p)) * 3;
        float x = src[0], y = src[1], z = src[2];
        uint8_t mt = umeta[ll];
        int lab = mt & 3, valid = (mt >> 2) & 1;
        float4 v; v.x = x; v.y = y; v.z = z;
        v.w = __uint_as_float((uint32_t)(b | (valid << 1)));
        spts[rank] = v;
        slab[rank] = (uint8_t)lab;
        sorder[rank] = (uint16_t)ll;
        if (valid) {
            int cl = (b << 12) | (cellco(z) << 8) | (cellco(y) << 4) | cellco(x);
            atomicAdd(&cellcnt[cl], 1);
        }
    }
}

// ---------------- g2: exclusive scan (8193 entries) + zero counts for reuse --
__global__ void g2_scan(int* __restrict__ cellcnt, int* __restrict__ cellstart) {
    __shared__ int part[256];
    __shared__ int poff[256];
    int t = threadIdx.x;
    int base = t * 32;
    int loc[32];
    int s = 0;
    for (int k = 0; k < 32; ++k) { loc[k] = cellcnt[base + k]; s += loc[k]; }
    part[t] = s;
    __syncthreads();
    if (t == 0) {
        int run = 0;
        for (int q = 0; q < 256; ++q) { poff[q] = run; run += part[q]; }
    }
    __syncthreads();
    int run = poff[t];
    for (int k = 0; k < 32; ++k) {
        cellstart[base + k] = run; run += loc[k];
        cellcnt[base + k] = 0;               // reuse as fill counters in g3
    }
    if (t == 255) cellstart[8192] = run;     // sentinel = V (valid count)
}

// ---------------- g3: scatter coords into cell-ordered float4 list ----------
__global__ void g3_scatter(const float4* __restrict__ spts, const int* __restrict__ cellstart,
                           int* __restrict__ cellfill, float4* __restrict__ cellxyz) {
    int pos = blockIdx.x * blockDim.x + threadIdx.x;
    if (pos >= L_TOT) return;
    float4 v = spts[pos];
    uint32_t w = __float_as_uint(v.w);
    if (!(w & 2u)) return;                   // invalid
    int b = (int)(w & 1u);
    int cl = (b << 12) | (cellco(v.z) << 8) | (cellco(v.y) << 4) | cellco(v.x);
    int slot = atomicAdd(&cellfill[cl], 1);
    float4 o; o.x = v.x; o.y = v.y; o.z = v.z; o.w = __uint_as_float((uint32_t)pos);
    cellxyz[cellstart[cl] + slot] = o;
}

// ---------------- k3: fixed-window pipelined greedy (single block) -----------
// Phase ph resolves sorted positions [128ph, 128ph+128). Wave0: aliveness from
// rem bits (batches <= ph-2 fully applied) + patch vs batch ph-1 (in flight),
// serial exact resolve -> batch ph; prefetches window ph+1 into registers.
// Waves 1..15: apply batch ph-1 to rem via cell lists. One barrier per phase.
__global__ void __launch_bounds__(1024) k3_greedy(
    const float4* __restrict__ spts, const uint8_t* __restrict__ slab,
    const uint16_t* __restrict__ sorder,
    const int* __restrict__ cellstart, const float4* __restrict__ cellxyz,
    uint16_t* __restrict__ sample) {
    __shared__ uint32_t rem[512];            // remaining bitmask by sorted position
    __shared__ uint16_t cs16[8193];          // cellstart (u16), sentinel at [8192]
    __shared__ uint8_t  slds[L_TOT];         // labels by sorted position (ordinal radii)
    __shared__ float4   pkd[2][128];         // x,y,z,r2 pick batches (double buffer)
    __shared__ int      pkb[2][128];         // pick batch id
    __shared__ int      pkn[2];

    const int t = threadIdx.x;
    const int V = cellstart[8192];
    const int NPH = (V + 127) >> 7;

    // wave0 prologue prefetch (window 0) — overlaps LDS init
    float4 cv0 = make_float4(0,0,0,0), cv1 = make_float4(0,0,0,0);
    int cord0 = 0, cord1 = 0;
    if (t < 64) {
        cv0 = spts[t]; cv1 = spts[64 + t];
        cord0 = (int)sorder[t]; cord1 = (int)sorder[64 + t];
    }
    for (int j = t; j < 8193; j += 1024) cs16[j] = (uint16_t)cellstart[j];
    for (int j = t; j < L_TOT; j += 1024) slds[j] = slab[j];
    for (int w = t; w < 512; w += 1024) {
        int lo = w * 32;
        uint32_t m;
        if (V >= lo + 32) m = 0xFFFFFFFFu;
        else if (V <= lo) m = 0u;
        else m = (1u << (V - lo)) - 1u;
        rem[w] = m;                          // valid points occupy positions [0, V)
    }
    if (t < 2) pkn[t] = 0;
    __syncthreads();

    int ii = 0;                              // pick ordinal (uniform in wave 0)
    for (int ph = 0; ph < NPH; ++ph) {
        const int cur = ph & 1, prv = cur ^ 1;
        if (t < 64) {
            // ---- issue prefetch for window ph+1 (used next phase) ----
            const int nb = (ph + 1) << 7;
            int q0 = nb + t;       q0 = q0 > (L_TOT - 1) ? (L_TOT - 1) : q0;
            int q1 = nb + 64 + t;  q1 = q1 > (L_TOT - 1) ? (L_TOT - 1) : q1;
            float4 nv0 = spts[q0], nv1 = spts[q1];
            int nord0 = (int)sorder[q0], nord1 = (int)sorder[q1];

            // ---- per-ordinal radii for this window's picks ----
            int o0 = ii + t;      o0 = o0 > (L_TOT - 1) ? (L_TOT - 1) : o0;
            int o1 = ii + 64 + t; o1 = o1 > (L_TOT - 1) ? (L_TOT - 1) : o1;
            float cr0 = rad2((int)slds[o0]);
            float cr1 = rad2((int)slds[o1]);

            // ---- aliveness: rem bit + patch vs in-flight batch (ph-1) ----
            const int pos0 = (ph << 7) + t, pos1 = pos0 + 64;
            bool a0 = (pos0 < V) && ((rem[pos0 >> 5] >> (pos0 & 31)) & 1u);
            bool a1 = (pos1 < V) && ((rem[pos1 >> 5] >> (pos1 & 31)) & 1u);
            const int cb0 = cord0 >> 13, cb1 = cord1 >> 13;
            const int m = pkn[prv];
            for (int j = 0; j < m; ++j) {
                float4 pk = pkd[prv][j];
                int pb = pkb[prv][j];
                if (a0 && cb0 == pb &&
                    d2f(cv0.x, cv0.y, cv0.z, pk.x, pk.y, pk.z) <= pk.w) a0 = false;
                if (a1 && cb1 == pb &&
                    d2f(cv1.x, cv1.y, cv1.z, pk.x, pk.y, pk.z) <= pk.w) a1 = false;
            }
            // ---- serial exact resolve (strict sorted order within window) ----
            unsigned long long am0 = __ballot(a0 ? 1 : 0);
            unsigned long long am1 = __ballot(a1 ? 1 : 0);
            int np = 0;
            const int ii0 = ii;
            while (am0 | am1) {
                const int js = am0 ? 0 : 1;
                const int jl = (int)__builtin_ctzll(am0 ? am0 : am1);
                float px = __shfl(js ? cv1.x : cv0.x, jl);
                float py = __shfl(js ? cv1.y : cv0.y, jl);
                float pz = __shfl(js ? cv1.z : cv0.z, jl);
                int   pb = __shfl(js ? cb1 : cb0, jl);
                float r2 = (np & 64) ? __shfl(cr1, np & 63) : __shfl(cr0, np & 63);
                if (t == jl) {
                    float x_ = js ? cv1.x : cv0.x;
                    float y_ = js ? cv1.y : cv0.y;
                    float z_ = js ? cv1.z : cv0.z;
                    int   b_ = js ? cb1 : cb0;
                    int   o_ = js ? cord1 : cord0;
                    pkd[cur][np] = make_float4(x_, y_, z_, r2);
                    pkb[cur][np] = b_;
                    sample[b_ * L_TOT + ii0 + np] = (uint16_t)(o_ & (NPT - 1));
                }
                if (a0 && cb0 == pb && d2f(cv0.x, cv0.y, cv0.z, px, py, pz) <= r2) a0 = false;
                if (a1 && cb1 == pb && d2f(cv1.x, cv1.y, cv1.z, px, py, pz) <= r2) a1 = false;
                ++np;
                am0 = __ballot(a0 ? 1 : 0);
                am1 = __ballot(a1 ? 1 : 0);
            }
            ii = ii0 + np;
            if (t == 0) pkn[cur] = np;
            // rotate prefetched window
            cv0 = nv0; cv1 = nv1; cord0 = nord0; cord1 = nord1;
        } else {
            // ---- waves 1..15: apply suppression of batch ph-1 ----
            const int np = pkn[prv];
            if (np > 0) {
                const int tid = t - 64;                  // 0..959
                const int ntask = np * 216;              // 27 cells x 8-way split
                for (int task = tid; task < ntask; task += 960) {
                    int sub = task & 7;
                    int pc = task >> 3;
                    int p = pc / 27;
                    int c = pc - p * 27;
                    float4 pv = pkd[prv][p];
                    int pb_ = pkb[prv][p];
                    float r2 = pv.w;
                    int cx = cellco(pv.x) + (c % 3) - 1;
                    int cy = cellco(pv.y) + ((c / 3) % 3) - 1;
                    int cz = cellco(pv.z) + (c / 9) - 1;
                    if ((unsigned)cx > 15u || (unsigned)cy > 15u || (unsigned)cz > 15u) continue;
                    // conservative cell-box cull (margin >> any rounding diff)
                    float lox = -6.4f + 0.8f * cx, hix = lox + 0.8f;
                    float loy = -6.4f + 0.8f * cy, hiy = loy + 0.8f;
                    float loz = -6.4f + 0.8f * cz, hiz = loz + 0.8f;
                    if (cx == 0) lox = -1e30f;  if (cx == 15) hix = 1e30f;
                    if (cy == 0) loy = -1e30f;  if (cy == 15) hiy = 1e30f;
                    if (cz == 0) loz = -1e30f;  if (cz == 15) hiz = 1e30f;
                    float dx = fmaxf(fmaxf(lox - pv.x, pv.x - hix), 0.0f);
                    float dy = fmaxf(fmaxf(loy - pv.y, pv.y - hiy), 0.0f);
                    float dz = fmaxf(fmaxf(loz - pv.z, pv.z - hiz), 0.0f);
                    if (dx * dx + dy * dy + dz * dz > r2 + 0.02f) continue;
                    int cl = (pb_ << 12) | (cz << 8) | (cy << 4) | cx;
                    int st = (int)cs16[cl];
                    int en = (int)cs16[cl + 1];
                    for (int k = st + sub; k < en; k += 8) {
                        float4 q = cellxyz[k];
                        float d2 = d2f(q.x, q.y, q.z, pv.x, pv.y, pv.z);
                        if (d2 <= r2) {
                            uint32_t qp = __float_as_uint(q.w);
                            atomicAnd(&rem[qp >> 5], ~(1u << (qp & 31)));
                        }
                    }
                }
            }
        }
        __syncthreads();
    }
}

// ---------------- k4: write outputs ----------------
__global__ void k4_out(const float* __restrict__ xyz, const uint16_t* __restrict__ sample,
                       float* __restrict__ out) {
    int s = blockIdx.x * blockDim.x + threadIdx.x;
    if (s >= 2 * L_TOT) return;
    int idx = (int)sample[s];
    int b = s >> 14;
    const float* src = xyz + ((size_t)(b * NPT + idx)) * 3;
    float* dst = out + (size_t)s * 3;
    dst[0] = src[0]; dst[1] = src[1]; dst[2] = src[2];
    out[3 * 2 * L_TOT + s] = (float)idx;   // sample_idx as float32 values
}

extern "C" void kernel_launch(void* const* d_in, const int* in_sizes, int n_in,
                              void* d_out, int out_size, void* d_ws, size_t ws_size,
                              hipStream_t stream) {
    const float* xyz = (const float*)d_in[0];
    const float* cls = (const float*)d_in[1];
    float* out = (float*)d_out;
    char* ws = (char*)d_ws;
    // layout:
    float4*   spts    = (float4*)  (ws + 0);        // 262144
    uint8_t*  slab    = (uint8_t*) (ws + 262144);   // 16384
    uint16_t* sorder  = (uint16_t*)(ws + 278528);   // 32768
    int*      cellcnt = (int*)     (ws + 311296);   // 32768 (reused as fill counters)
    int*      cellst  = (int*)     (ws + 344064);   // 36864 (8193 ints + pad)
    float4*   cellxyz = (float4*)  (ws + 380928);   // 262144
    uint64_t* keys    = (uint64_t*)(ws + 380928);   // alias: dead after k2
    uint8_t*  umeta   = (uint8_t*) (ws + 512000);   // alias: dead after k2
    uint16_t* sample  = (uint16_t*)(ws + 643072);   // 65536

    k1_keys   <<<64,  256, 0, stream>>>(cls, keys, umeta, sample, cellcnt);
    k2_sort   <<<512, 256, 0, stream>>>(keys, umeta, xyz, spts, slab, sorder, cellcnt);
    g2_scan   <<<1,   256, 0, stream>>>(cellcnt, cellst);
    g3_scatter<<<64,  256, 0, stream>>>(spts, cellst, cellcnt, cellxyz);
    k3_greedy <<<1,  1024, 0, stream>>>(spts, slab, sorder, cellst, cellxyz, sample);
    k4_out    <<<128, 256, 0, stream>>>(xyz, sample, out);
}

// Round 5
// 616.238 us; speedup vs baseline: 1.0621x; 1.0621x over previous
//
#include <hip/hip_runtime.h>
#include <stdint.h>

// InstanceSampling: greedy per-class radius suppression (exact reference semantics).
// B=2, N=8192, C=3, L=16384. RADII = {0.5,0.6,0.7}; radius of pick #i is
// RADII[label of sorted slot i] (reference quirk: indexed by pick ORDINAL).
//
// k1 init+keys -> k2 O(L^2) rank sort -> g2 scan -> g3 cell scatter ->
// k3 greedy (single block; fixed 128-wide windows; wave0 resolves window ph
// with a readlane+2-wide-speculation serial loop while waves 1..15 apply
// suppression of batch ph-1 via cell lists) -> k4 out.

#define L_TOT 16384
#define NPT   8192

__device__ __forceinline__ int cellco(float v) {
    int c = (int)floorf((v + 6.4f) * 1.25f);   // cell size 0.8 >= max radius 0.7
    return c < 0 ? 0 : (c > 15 ? 15 : c);
}
__device__ __forceinline__ float d2f(float ax, float ay, float az,
                                     float bx, float by, float bz) {
    float dx = __fsub_rn(ax, bx), dy = __fsub_rn(ay, by), dz = __fsub_rn(az, bz);
    return __fadd_rn(__fadd_rn(__fmul_rn(dx, dx), __fmul_rn(dy, dy)), __fmul_rn(dz, dz));
}
__device__ __forceinline__ float rad2(int lb) {
    float rr = (lb == 0) ? 0.5f : ((lb == 1) ? 0.6f : 0.7f);
    return __fmul_rn(rr, rr);
}
__device__ __forceinline__ float rlf(float v, int l) {      // SGPR broadcast (uniform l)
    return __uint_as_float(__builtin_amdgcn_readlane(__float_as_uint(v), l));
}
__device__ __forceinline__ int rli(int v, int l) {
    return (int)__builtin_amdgcn_readlane((uint32_t)v, l);
}

// ---------------- k1: init + per-point keys ----------------
__global__ void k1_keys(const float* __restrict__ cls, uint64_t* __restrict__ keys,
                        uint8_t* __restrict__ umeta, uint16_t* __restrict__ sample,
                        int* __restrict__ cellcnt) {
    int l = blockIdx.x * blockDim.x + threadIdx.x;
    if (l >= L_TOT) return;
    ((uint32_t*)sample)[l] = 0;                  // zero 2*L u16
    if (l < 8192) cellcnt[l] = 0;
    float c0 = cls[l * 3 + 0], c1 = cls[l * 3 + 1], c2 = cls[l * 3 + 2];
    float m = c0; int lab = 0;
    if (c1 > m) { m = c1; lab = 1; }   // strict > : first-max, matches jnp.argmax
    if (c2 > m) { m = c2; lab = 2; }
    int valid = (m >= 0.0f) ? 1 : 0;   // sigmoid(m) >= 0.5  <=>  m >= 0
    float keyf = valid ? m : -__builtin_inff();
    uint32_t u = __float_as_uint(keyf);
    uint32_t o = (u & 0x80000000u) ? ~u : (u | 0x80000000u); // order-preserving map
    keys[l] = ((uint64_t)(~o) << 32) | (uint32_t)l;          // asc == desc score, stable
    umeta[l] = (uint8_t)(lab | (valid << 2));
}

// ---------------- k2: O(L^2) rank sort + build sorted arrays + cell counts ----
__global__ void __launch_bounds__(256) k2_sort(
    const uint64_t* __restrict__ keys, const uint8_t* __restrict__ umeta,
    const float* __restrict__ xyz,
    float4* __restrict__ spts, uint8_t* __restrict__ slab, uint16_t* __restrict__ sorder,
    int* __restrict__ cellcnt) {
    __shared__ uint64_t tile[2048];
    __shared__ int psum[256];
    const int t = threadIdx.x;
    const int elem = t & 31, part = t >> 5;
    const int l = blockIdx.x * 32 + elem;
    const uint64_t myk = keys[l];
    int cnt = 0;
    for (int t0 = 0; t0 < L_TOT; t0 += 2048) {
        for (int j = t; j < 2048; j += 256) tile[j] = keys[t0 + j];
        __syncthreads();
        const int b0 = part * 256;
        #pragma unroll 4
        for (int j = 0; j < 256; ++j) cnt += (tile[b0 + j] < myk) ? 1 : 0;
        __syncthreads();
    }
    psum[t] = cnt;
    __syncthreads();
    if (t < 32) {
        int rank = 0;
        #pragma unroll
        for (int q = 0; q < 8; ++q) rank += psum[q * 32 + t];
        const int ll = blockIdx.x * 32 + t;
        int b = ll >> 13, p = ll & (NPT - 1);
        const float* src = xyz + ((size_t)(b * NPT + p)) * 3;
        float x = src[0], y = src[1], z = src[2];
        uint8_t mt = umeta[ll];
        int lab = mt & 3, valid = (mt >> 2) & 1;
        float4 v; v.x = x; v.y = y; v.z = z;
        v.w = __uint_as_float((uint32_t)(b | (valid << 1)));
        spts[rank] = v;
        slab[rank] = (uint8_t)lab;
        sorder[rank] = (uint16_t)ll;
        if (valid) {
            int cl = (b << 12) | (cellco(z) << 8) | (cellco(y) << 4) | cellco(x);
            atomicAdd(&cellcnt[cl], 1);
        }
    }
}

// ---------------- g2: exclusive scan (8193 entries) + zero counts for reuse --
__global__ void g2_scan(int* __restrict__ cellcnt, int* __restrict__ cellstart) {
    __shared__ int part[256];
    __shared__ int poff[256];
    int t = threadIdx.x;
    int base = t * 32;
    int loc[32];
    int s = 0;
    for (int k = 0; k < 32; ++k) { loc[k] = cellcnt[base + k]; s += loc[k]; }
    part[t] = s;
    __syncthreads();
    if (t == 0) {
        int run = 0;
        for (int q = 0; q < 256; ++q) { poff[q] = run; run += part[q]; }
    }
    __syncthreads();
    int run = poff[t];
    for (int k = 0; k < 32; ++k) {
        cellstart[base + k] = run; run += loc[k];
        cellcnt[base + k] = 0;               // reuse as fill counters in g3
    }
    if (t == 255) cellstart[8192] = run;     // sentinel = V (valid count)
}

// ---------------- g3: scatter coords into cell-ordered float4 list ----------
__global__ void g3_scatter(const float4* __restrict__ spts, const int* __restrict__ cellstart,
                           int* __restrict__ cellfill, float4* __restrict__ cellxyz) {
    int pos = blockIdx.x * blockDim.x + threadIdx.x;
    if (pos >= L_TOT) return;
    float4 v = spts[pos];
    uint32_t w = __float_as_uint(v.w);
    if (!(w & 2u)) return;                   // invalid
    int b = (int)(w & 1u);
    int cl = (b << 12) | (cellco(v.z) << 8) | (cellco(v.y) << 4) | cellco(v.x);
    int slot = atomicAdd(&cellfill[cl], 1);
    float4 o; o.x = v.x; o.y = v.y; o.z = v.z; o.w = __uint_as_float((uint32_t)pos);
    cellxyz[cellstart[cl] + slot] = o;
}

// ---------------- k3: fixed-window pipelined greedy (single block) -----------
__global__ void __launch_bounds__(1024) k3_greedy(
    const float4* __restrict__ spts, const uint8_t* __restrict__ slab,
    const uint16_t* __restrict__ sorder,
    const int* __restrict__ cellstart, const float4* __restrict__ cellxyz,
    uint16_t* __restrict__ sample) {
    __shared__ uint32_t rem[512];            // remaining bitmask by sorted position
    __shared__ uint16_t cs16[8193];          // cellstart (u16), sentinel at [8192]
    __shared__ uint8_t  slds[L_TOT];         // labels by sorted position (ordinal radii)
    __shared__ float4   pkd[2][128];         // x,y,z,r2 pick batches (double buffer)
    __shared__ int      pkb[2][128];         // pick batch id
    __shared__ int      pkn[2];

    const int t = threadIdx.x;
    const int V = cellstart[8192];
    const int NPH = (V + 127) >> 7;

    // wave0 prologue prefetch (window 0) — overlaps LDS init
    float4 cv0 = make_float4(0,0,0,0), cv1 = make_float4(0,0,0,0);
    int cord0 = 0, cord1 = 0;
    if (t < 64) {
        cv0 = spts[t]; cv1 = spts[64 + t];
        cord0 = (int)sorder[t]; cord1 = (int)sorder[64 + t];
    }
    for (int j = t; j < 8193; j += 1024) cs16[j] = (uint16_t)cellstart[j];
    for (int j = t; j < L_TOT; j += 1024) slds[j] = slab[j];
    for (int w = t; w < 512; w += 1024) {
        int lo = w * 32;
        uint32_t m;
        if (V >= lo + 32) m = 0xFFFFFFFFu;
        else if (V <= lo) m = 0u;
        else m = (1u << (V - lo)) - 1u;
        rem[w] = m;                          // valid points occupy positions [0, V)
    }
    if (t < 2) pkn[t] = 0;
    __syncthreads();

    int ii = 0;                              // pick ordinal (uniform in wave 0)
    for (int ph = 0; ph < NPH; ++ph) {
        const int cur = ph & 1, prv = cur ^ 1;
        if (t < 64) {
            // ---- issue prefetch for window ph+1 (used next phase) ----
            const int nb = (ph + 1) << 7;
            int q0 = nb + t;       q0 = q0 > (L_TOT - 1) ? (L_TOT - 1) : q0;
            int q1 = nb + 64 + t;  q1 = q1 > (L_TOT - 1) ? (L_TOT - 1) : q1;
            float4 nv0 = spts[q0], nv1 = spts[q1];
            int nord0 = (int)sorder[q0], nord1 = (int)sorder[q1];

            // ---- per-ordinal radii for this window's picks ----
            int o0 = ii + t;      o0 = o0 > (L_TOT - 1) ? (L_TOT - 1) : o0;
            int o1 = ii + 64 + t; o1 = o1 > (L_TOT - 1) ? (L_TOT - 1) : o1;
            float cr0 = rad2((int)slds[o0]);
            float cr1 = rad2((int)slds[o1]);

            // ---- aliveness: rem bit + patch vs in-flight batch (ph-1) ----
            const int pos0 = (ph << 7) + t, pos1 = pos0 + 64;
            bool a0 = (pos0 < V) && ((rem[pos0 >> 5] >> (pos0 & 31)) & 1u);
            bool a1 = (pos1 < V) && ((rem[pos1 >> 5] >> (pos1 & 31)) & 1u);
            const int cb0 = cord0 >> 13, cb1 = cord1 >> 13;
            const int m = pkn[prv];
            for (int j = 0; j < m; ++j) {
                float4 pk = pkd[prv][j];
                int pb = pkb[prv][j];
                if (a0 && cb0 == pb &&
                    d2f(cv0.x, cv0.y, cv0.z, pk.x, pk.y, pk.z) <= pk.w) a0 = false;
                if (a1 && cb1 == pb &&
                    d2f(cv1.x, cv1.y, cv1.z, pk.x, pk.y, pk.z) <= pk.w) a1 = false;
            }

            // ---- serial resolve: readlane broadcast + 2-wide speculation ----
            int np = 0;
            const int ii0 = ii;
            // half 0 (updates a0 and a1)
            {
                unsigned long long am = __ballot(a0 ? 1 : 0);
                while (am) {
                    const int jl0 = (int)__builtin_ctzll(am);
                    const unsigned long long am2 = am & (am - 1);
                    const bool has2 = (am2 != 0ull);
                    const int jl1 = has2 ? (int)__builtin_ctzll(am2) : jl0;
                    const float p0x = rlf(cv0.x, jl0), p0y = rlf(cv0.y, jl0), p0z = rlf(cv0.z, jl0);
                    const int   b0  = rli(cord0, jl0) >> 13;
                    const float p1x = rlf(cv0.x, jl1), p1y = rlf(cv0.y, jl1), p1z = rlf(cv0.z, jl1);
                    const int   b1  = rli(cord0, jl1) >> 13;
                    const float r2_0 = rlf((np & 64) ? cr1 : cr0, np & 63);
                    const int np1 = np + 1;
                    const float r2_1 = rlf((np1 & 64) ? cr1 : cr0, np1 & 63);
                    // uniform scalar check: does candidate jl1 survive pick jl0?
                    const bool kb = (b0 == b1) &&
                                    (d2f(p1x, p1y, p1z, p0x, p0y, p0z) <= r2_0);
                    const bool two = has2 && !kb;
                    if (t == jl0) {
                        pkd[cur][np] = make_float4(cv0.x, cv0.y, cv0.z, r2_0);
                        pkb[cur][np] = b0;
                        sample[b0 * L_TOT + ii0 + np] = (uint16_t)(cord0 & (NPT - 1));
                    }
                    if (two && t == jl1) {
                        pkd[cur][np1] = make_float4(cv0.x, cv0.y, cv0.z, r2_1);
                        pkb[cur][np1] = b1;
                        sample[b1 * L_TOT + ii0 + np1] = (uint16_t)(cord0 & (NPT - 1));
                    }
                    if (a0) {
                        if (cb0 == b0 && d2f(cv0.x, cv0.y, cv0.z, p0x, p0y, p0z) <= r2_0) a0 = false;
                        if (two && cb0 == b1 && d2f(cv0.x, cv0.y, cv0.z, p1x, p1y, p1z) <= r2_1) a0 = false;
                    }
                    if (a1) {
                        if (cb1 == b0 && d2f(cv1.x, cv1.y, cv1.z, p0x, p0y, p0z) <= r2_0) a1 = false;
                        if (two && cb1 == b1 && d2f(cv1.x, cv1.y, cv1.z, p1x, p1y, p1z) <= r2_1) a1 = false;
                    }
                    np += two ? 2 : 1;
                    am = __ballot(a0 ? 1 : 0);
                }
            }
            // half 1 (updates a1 only)
            {
                unsigned long long am = __ballot(a1 ? 1 : 0);
                while (am) {
                    const int jl0 = (int)__builtin_ctzll(am);
                    const unsigned long long am2 = am & (am - 1);
                    const bool has2 = (am2 != 0ull);
                    const int jl1 = has2 ? (int)__builtin_ctzll(am2) : jl0;
                    const float p0x = rlf(cv1.x, jl0), p0y = rlf(cv1.y, jl0), p0z = rlf(cv1.z, jl0);
                    const int   b0  = rli(cord1, jl0) >> 13;
                    const float p1x = rlf(cv1.x, jl1), p1y = rlf(cv1.y, jl1), p1z = rlf(cv1.z, jl1);
                    const int   b1  = rli(cord1, jl1) >> 13;
                    const float r2_0 = rlf((np & 64) ? cr1 : cr0, np & 63);
                    const int np1 = np + 1;
                    const float r2_1 = rlf((np1 & 64) ? cr1 : cr0, np1 & 63);
                    const bool kb = (b0 == b1) &&
                                    (d2f(p1x, p1y, p1z, p0x, p0y, p0z) <= r2_0);
                    const bool two = has2 && !kb;
                    if (t == jl0) {
                        pkd[cur][np] = make_float4(cv1.x, cv1.y, cv1.z, r2_0);
                        pkb[cur][np] = b0;
                        sample[b0 * L_TOT + ii0 + np] = (uint16_t)(cord1 & (NPT - 1));
                    }
                    if (two && t == jl1) {
                        pkd[cur][np1] = make_float4(cv1.x, cv1.y, cv1.z, r2_1);
                        pkb[cur][np1] = b1;
                        sample[b1 * L_TOT + ii0 + np1] = (uint16_t)(cord1 & (NPT - 1));
                    }
                    if (a1) {
                        if (cb1 == b0 && d2f(cv1.x, cv1.y, cv1.z, p0x, p0y, p0z) <= r2_0) a1 = false;
                        if (two && cb1 == b1 && d2f(cv1.x, cv1.y, cv1.z, p1x, p1y, p1z) <= r2_1) a1 = false;
                    }
                    np += two ? 2 : 1;
                    am = __ballot(a1 ? 1 : 0);
                }
            }
            ii = ii0 + np;
            if (t == 0) pkn[cur] = np;
            // rotate prefetched window
            cv0 = nv0; cv1 = nv1; cord0 = nord0; cord1 = nord1;
        } else {
            // ---- waves 1..15: apply suppression of batch ph-1 ----
            const int np = pkn[prv];
            if (np > 0) {
                const int tid = t - 64;                  // 0..959
                const int ntask = np * 216;              // 27 cells x 8-way split
                for (int task = tid; task < ntask; task += 960) {
                    int sub = task & 7;
                    int pc = task >> 3;
                    int p = pc / 27;
                    int c = pc - p * 27;
                    float4 pv = pkd[prv][p];
                    int pb_ = pkb[prv][p];
                    float r2 = pv.w;
                    int cx = cellco(pv.x) + (c % 3) - 1;
                    int cy = cellco(pv.y) + ((c / 3) % 3) - 1;
                    int cz = cellco(pv.z) + (c / 9) - 1;
                    if ((unsigned)cx > 15u || (unsigned)cy > 15u || (unsigned)cz > 15u) continue;
                    // conservative cell-box cull (margin >> any rounding diff)
                    float lox = -6.4f + 0.8f * cx, hix = lox + 0.8f;
                    float loy = -6.4f + 0.8f * cy, hiy = loy + 0.8f;
                    float loz = -6.4f + 0.8f * cz, hiz = loz + 0.8f;
                    if (cx == 0) lox = -1e30f;  if (cx == 15) hix = 1e30f;
                    if (cy == 0) loy = -1e30f;  if (cy == 15) hiy = 1e30f;
                    if (cz == 0) loz = -1e30f;  if (cz == 15) hiz = 1e30f;
                    float dx = fmaxf(fmaxf(lox - pv.x, pv.x - hix), 0.0f);
                    float dy = fmaxf(fmaxf(loy - pv.y, pv.y - hiy), 0.0f);
                    float dz = fmaxf(fmaxf(loz - pv.z, pv.z - hiz), 0.0f);
                    if (dx * dx + dy * dy + dz * dz > r2 + 0.02f) continue;
                    int cl = (pb_ << 12) | (cz << 8) | (cy << 4) | cx;
                    int st = (int)cs16[cl];
                    int en = (int)cs16[cl + 1];
                    for (int k = st + sub; k < en; k += 8) {
                        float4 q = cellxyz[k];
                        float d2 = d2f(q.x, q.y, q.z, pv.x, pv.y, pv.z);
                        if (d2 <= r2) {
                            uint32_t qp = __float_as_uint(q.w);
                            atomicAnd(&rem[qp >> 5], ~(1u << (qp & 31)));
                        }
                    }
                }
            }
        }
        __syncthreads();
    }
}

// ---------------- k4: write outputs ----------------
__global__ void k4_out(const float* __restrict__ xyz, const uint16_t* __restrict__ sample,
                       float* __restrict__ out) {
    int s = blockIdx.x * blockDim.x + threadIdx.x;
    if (s >= 2 * L_TOT) return;
    int idx = (int)sample[s];
    int b = s >> 14;
    const float* src = xyz + ((size_t)(b * NPT + idx)) * 3;
    float* dst = out + (size_t)s * 3;
    dst[0] = src[0]; dst[1] = src[1]; dst[2] = src[2];
    out[3 * 2 * L_TOT + s] = (float)idx;   // sample_idx as float32 values
}

extern "C" void kernel_launch(void* const* d_in, const int* in_sizes, int n_in,
                              void* d_out, int out_size, void* d_ws, size_t ws_size,
                              hipStream_t stream) {
    const float* xyz = (const float*)d_in[0];
    const float* cls = (const float*)d_in[1];
    float* out = (float*)d_out;
    char* ws = (char*)d_ws;
    // layout:
    float4*   spts    = (float4*)  (ws + 0);        // 262144
    uint8_t*  slab    = (uint8_t*) (ws + 262144);   // 16384
    uint16_t* sorder  = (uint16_t*)(ws + 278528);   // 32768
    int*      cellcnt = (int*)     (ws + 311296);   // 32768 (reused as fill counters)
    int*      cellst  = (int*)     (ws + 344064);   // 36864 (8193 ints + pad)
    float4*   cellxyz = (float4*)  (ws + 380928);   // 262144
    uint64_t* keys    = (uint64_t*)(ws + 380928);   // alias: dead after k2
    uint8_t*  umeta   = (uint8_t*) (ws + 512000);   // alias: dead after k2
    uint16_t* sample  = (uint16_t*)(ws + 643072);   // 65536

    k1_keys   <<<64,  256, 0, stream>>>(cls, keys, umeta, sample, cellcnt);
    k2_sort   <<<512, 256, 0, stream>>>(keys, umeta, xyz, spts, slab, sorder, cellcnt);
    g2_scan   <<<1,   256, 0, stream>>>(cellcnt, cellst);
    g3_scatter<<<64,  256, 0, stream>>>(spts, cellst, cellcnt, cellxyz);
    k3_greedy <<<1,  1024, 0, stream>>>(spts, slab, sorder, cellst, cellxyz, sample);
    k4_out    <<<128, 256, 0, stream>>>(xyz, sample, out);
}

// Round 6
// 508.742 us; speedup vs baseline: 1.2866x; 1.2113x over previous
//
#include <hip/hip_runtime.h>
#include <stdint.h>

// InstanceSampling: greedy per-class radius suppression (exact reference semantics).
// B=2, N=8192, C=3, L=16384. RADII = {0.5,0.6,0.7}; radius of pick #i is
// RADII[label of sorted slot i] (reference quirk: indexed by pick ORDINAL).
//
// k1 init+keys -> k2 O(L^2) rank sort -> g2 scan -> g3 cell scatter ->
// k3 greedy (single block; fixed 128-wide windows; wave0 resolves window ph
// [readlane + 2-wide speculation] while waves 1..15 apply suppression of
// batch ph-1 by scanning a QUANTIZED LDS-RESIDENT copy of the cell lists;
// conservative band test, exact f32 fallback only for borderline) -> k4 out.

#define L_TOT 16384
#define NPT   8192

__device__ __forceinline__ int cellco(float v) {
    int c = (int)floorf((v + 6.4f) * 1.25f);   // cell size 0.8 >= max radius 0.7
    return c < 0 ? 0 : (c > 15 ? 15 : c);
}
__device__ __forceinline__ float d2f(float ax, float ay, float az,
                                     float bx, float by, float bz) {
    float dx = __fsub_rn(ax, bx), dy = __fsub_rn(ay, by), dz = __fsub_rn(az, bz);
    return __fadd_rn(__fadd_rn(__fmul_rn(dx, dx), __fmul_rn(dy, dy)), __fmul_rn(dz, dz));
}
__device__ __forceinline__ float rad2(int lb) {
    float rr = (lb == 0) ? 0.5f : ((lb == 1) ? 0.6f : 0.7f);
    return __fmul_rn(rr, rr);
}
__device__ __forceinline__ float rlf(float v, int l) {      // SGPR broadcast (uniform l)
    return __uint_as_float(__builtin_amdgcn_readlane(__float_as_uint(v), l));
}
__device__ __forceinline__ int rli(int v, int l) {
    return (int)__builtin_amdgcn_readlane((uint32_t)v, l);
}

// ---------------- k1: init + per-point keys ----------------
__global__ void k1_keys(const float* __restrict__ cls, uint64_t* __restrict__ keys,
                        uint8_t* __restrict__ umeta, uint16_t* __restrict__ sample,
                        int* __restrict__ cellcnt, uint32_t* __restrict__ slab2) {
    int l = blockIdx.x * blockDim.x + threadIdx.x;
    if (l >= L_TOT) return;
    ((uint32_t*)sample)[l] = 0;                  // zero 2*L u16
    if (l < 8192) cellcnt[l] = 0;
    if (l < 1024) slab2[l] = 0;
    float c0 = cls[l * 3 + 0], c1 = cls[l * 3 + 1], c2 = cls[l * 3 + 2];
    float m = c0; int lab = 0;
    if (c1 > m) { m = c1; lab = 1; }   // strict > : first-max, matches jnp.argmax
    if (c2 > m) { m = c2; lab = 2; }
    int valid = (m >= 0.0f) ? 1 : 0;   // sigmoid(m) >= 0.5  <=>  m >= 0
    float keyf = valid ? m : -__builtin_inff();
    uint32_t u = __float_as_uint(keyf);
    uint32_t o = (u & 0x80000000u) ? ~u : (u | 0x80000000u); // order-preserving map
    keys[l] = ((uint64_t)(~o) << 32) | (uint32_t)l;          // asc == desc score, stable
    umeta[l] = (uint8_t)(lab | (valid << 2));
}

// ---------------- k2: O(L^2) rank sort + build sorted arrays + cell counts ----
__global__ void __launch_bounds__(256) k2_sort(
    const uint64_t* __restrict__ keys, const uint8_t* __restrict__ umeta,
    const float* __restrict__ xyz,
    float4* __restrict__ spts, uint32_t* __restrict__ slab2, uint16_t* __restrict__ sorder,
    int* __restrict__ cellcnt) {
    __shared__ uint64_t tile[2048];
    __shared__ int psum[256];
    const int t = threadIdx.x;
    const int elem = t & 31, part = t >> 5;
    const int l = blockIdx.x * 32 + elem;
    const uint64_t myk = keys[l];
    int cnt = 0;
    for (int t0 = 0; t0 < L_TOT; t0 += 2048) {
        for (int j = t; j < 2048; j += 256) tile[j] = keys[t0 + j];
        __syncthreads();
        const int b0 = part * 256;
        #pragma unroll 4
        for (int j = 0; j < 256; ++j) cnt += (tile[b0 + j] < myk) ? 1 : 0;
        __syncthreads();
    }
    psum[t] = cnt;
    __syncthreads();
    if (t < 32) {
        int rank = 0;
        #pragma unroll
        for (int q = 0; q < 8; ++q) rank += psum[q * 32 + t];
        const int ll = blockIdx.x * 32 + t;
        int b = ll >> 13, p = ll & (NPT - 1);
        const float* src = xyz + ((size_t)(b * NPT + p)) * 3;
        float x = src[0], y = src[1], z = src[2];
        uint8_t mt = umeta[ll];
        int lab = mt & 3, valid = (mt >> 2) & 1;
        float4 v; v.x = x; v.y = y; v.z = z;
        v.w = __uint_as_float((uint32_t)(b | (valid << 1)));
        spts[rank] = v;
        sorder[rank] = (uint16_t)ll;
        atomicOr(&slab2[rank >> 4], (uint32_t)lab << ((rank & 15) << 1));
        if (valid) {
            int cl = (b << 12) | (cellco(z) << 8) | (cellco(y) << 4) | cellco(x);
            atomicAdd(&cellcnt[cl], 1);
        }
    }
}

// ---------------- g2: exclusive scan (8193 entries) + zero counts for reuse --
__global__ void g2_scan(int* __restrict__ cellcnt, int* __restrict__ cellstart) {
    __shared__ int part[256];
    __shared__ int poff[256];
    int t = threadIdx.x;
    int base = t * 32;
    int loc[32];
    int s = 0;
    for (int k = 0; k < 32; ++k) { loc[k] = cellcnt[base + k]; s += loc[k]; }
    part[t] = s;
    __syncthreads();
    if (t == 0) {
        int run = 0;
        for (int q = 0; q < 256; ++q) { poff[q] = run; run += part[q]; }
    }
    __syncthreads();
    int run = poff[t];
    for (int k = 0; k < 32; ++k) {
        cellstart[base + k] = run; run += loc[k];
        cellcnt[base + k] = 0;               // reuse as fill counters in g3
    }
    if (t == 255) cellstart[8192] = run;     // sentinel = V (valid count)
}

// ---------------- g3: scatter coords into cell-ordered float4 list ----------
__global__ void g3_scatter(const float4* __restrict__ spts, const int* __restrict__ cellstart,
                           int* __restrict__ cellfill, float4* __restrict__ cellxyz) {
    int pos = blockIdx.x * blockDim.x + threadIdx.x;
    if (pos >= L_TOT) return;
    float4 v = spts[pos];
    uint32_t w = __float_as_uint(v.w);
    if (!(w & 2u)) return;                   // invalid
    int b = (int)(w & 1u);
    int cl = (b << 12) | (cellco(v.z) << 8) | (cellco(v.y) << 4) | cellco(v.x);
    int slot = atomicAdd(&cellfill[cl], 1);
    float4 o; o.x = v.x; o.y = v.y; o.z = v.z; o.w = __uint_as_float((uint32_t)pos);
    cellxyz[cellstart[cl] + slot] = o;
}

// ---------------- k3: fixed-window greedy, LDS-resident quantized scan -------
__global__ void __launch_bounds__(1024) k3_greedy(
    const float4* __restrict__ spts, const uint32_t* __restrict__ slab2,
    const uint16_t* __restrict__ sorder,
    const int* __restrict__ cellstart, const float4* __restrict__ cellxyz,
    uint16_t* __restrict__ sample) {
    __shared__ uint64_t qpack[16384];        // 131072 B: qx|qy<<16 | (qz|pos<<16)<<32
    __shared__ uint32_t rem[512];            //   2048 B: remaining by sorted position
    __shared__ uint32_t alive2[512];         //   2048 B: remaining by cell-entry index
    __shared__ uint16_t cs16[8194];          //  16388 B: cellstart u16 (+sentinel)
    __shared__ uint32_t slds2[1024];         //   4096 B: 2-bit labels by sorted pos
    __shared__ float4   pkd[2][128];         //   4096 B: pick x,y,z,r2 (dbuf)
    __shared__ int      pkb[2][128];         //   1024 B: pick batch
    __shared__ int      pkn[2];

    const int t = threadIdx.x;
    const int V = cellstart[8192];
    const int NPH = (V + 127) >> 7;

    // wave0 prologue prefetch (window 0) — loads in flight during LDS init
    float4 cv0 = make_float4(0,0,0,0), cv1 = make_float4(0,0,0,0);
    int cord0 = 0, cord1 = 0;
    if (t < 64) {
        cv0 = spts[t]; cv1 = spts[64 + t];
        cord0 = (int)sorder[t]; cord1 = (int)sorder[64 + t];
    }
    for (int j = t; j < 8193; j += 1024) cs16[j] = (uint16_t)cellstart[j];
    for (int j = t; j < 1024; j += 1024) slds2[j] = slab2[j];
    for (int k = t; k < V; k += 1024) {      // quantized LDS mirror of cellxyz
        float4 q = cellxyz[k];
        int qx = __float2int_rn(__fmul_rn(__fadd_rn(q.x, 8.0f), 4096.0f));
        int qy = __float2int_rn(__fmul_rn(__fadd_rn(q.y, 8.0f), 4096.0f));
        int qz = __float2int_rn(__fmul_rn(__fadd_rn(q.z, 8.0f), 4096.0f));
        qx = qx < 0 ? 0 : (qx > 65535 ? 65535 : qx);
        qy = qy < 0 ? 0 : (qy > 65535 ? 65535 : qy);
        qz = qz < 0 ? 0 : (qz > 65535 ? 65535 : qz);
        uint32_t pos = __float_as_uint(q.w);
        qpack[k] = ((uint64_t)(((uint32_t)qz) | (pos << 16)) << 32)
                 | ((uint32_t)qx | ((uint32_t)qy << 16));
    }
    for (int w = t; w < 512; w += 1024) {
        int lo = w * 32;
        uint32_t m;
        if (V >= lo + 32) m = 0xFFFFFFFFu;
        else if (V <= lo) m = 0u;
        else m = (1u << (V - lo)) - 1u;
        rem[w] = m;                          // by sorted position
        alive2[w] = m;                       // by cell-entry index (same count V)
    }
    if (t < 2) pkn[t] = 0;
    __syncthreads();

    int ii = 0;                              // pick ordinal (uniform in wave 0)
    for (int ph = 0; ph < NPH; ++ph) {
        const int cur = ph & 1, prv = cur ^ 1;
        if (t < 64) {
            // ---- issue prefetch for window ph+1 (used next phase) ----
            const int nb = (ph + 1) << 7;
            int q0 = nb + t;       q0 = q0 > (L_TOT - 1) ? (L_TOT - 1) : q0;
            int q1 = nb + 64 + t;  q1 = q1 > (L_TOT - 1) ? (L_TOT - 1) : q1;
            float4 nv0 = spts[q0], nv1 = spts[q1];
            int nord0 = (int)sorder[q0], nord1 = (int)sorder[q1];

            // ---- per-ordinal radii for this window's picks ----
            int o0 = ii + t;      o0 = o0 > (L_TOT - 1) ? (L_TOT - 1) : o0;
            int o1 = ii + 64 + t; o1 = o1 > (L_TOT - 1) ? (L_TOT - 1) : o1;
            float cr0 = rad2((int)((slds2[o0 >> 4] >> ((o0 & 15) << 1)) & 3u));
            float cr1 = rad2((int)((slds2[o1 >> 4] >> ((o1 & 15) << 1)) & 3u));

            // ---- aliveness: rem bit + patch vs in-flight batch (ph-1) ----
            const int pos0 = (ph << 7) + t, pos1 = pos0 + 64;
            bool a0 = (pos0 < V) && ((rem[pos0 >> 5] >> (pos0 & 31)) & 1u);
            bool a1 = (pos1 < V) && ((rem[pos1 >> 5] >> (pos1 & 31)) & 1u);
            const int cb0 = cord0 >> 13, cb1 = cord1 >> 13;
            if (__ballot((a0 ? 1 : 0) | (a1 ? 1 : 0))) {
                const int m = pkn[prv];
                for (int j = 0; j < m; ++j) {
                    float4 pk = pkd[prv][j];
                    int pb = pkb[prv][j];
                    if (a0 && cb0 == pb &&
                        d2f(cv0.x, cv0.y, cv0.z, pk.x, pk.y, pk.z) <= pk.w) a0 = false;
                    if (a1 && cb1 == pb &&
                        d2f(cv1.x, cv1.y, cv1.z, pk.x, pk.y, pk.z) <= pk.w) a1 = false;
                }
            }

            // ---- serial resolve: readlane broadcast + 2-wide speculation ----
            int np = 0;
            const int ii0 = ii;
            {
                unsigned long long am = __ballot(a0 ? 1 : 0);
                while (am) {
                    const int jl0 = (int)__builtin_ctzll(am);
                    const unsigned long long am2 = am & (am - 1);
                    const bool has2 = (am2 != 0ull);
                    const int jl1 = has2 ? (int)__builtin_ctzll(am2) : jl0;
                    const float p0x = rlf(cv0.x, jl0), p0y = rlf(cv0.y, jl0), p0z = rlf(cv0.z, jl0);
                    const int   b0  = rli(cord0, jl0) >> 13;
                    const float p1x = rlf(cv0.x, jl1), p1y = rlf(cv0.y, jl1), p1z = rlf(cv0.z, jl1);
                    const int   b1  = rli(cord0, jl1) >> 13;
                    const float r2_0 = rlf((np & 64) ? cr1 : cr0, np & 63);
                    const int np1 = np + 1;
                    const float r2_1 = rlf((np1 & 64) ? cr1 : cr0, np1 & 63);
                    const bool kb = (b0 == b1) &&
                                    (d2f(p1x, p1y, p1z, p0x, p0y, p0z) <= r2_0);
                    const bool two = has2 && !kb;
                    if (t == jl0) {
                        pkd[cur][np] = make_float4(cv0.x, cv0.y, cv0.z, r2_0);
                        pkb[cur][np] = b0;
                        sample[b0 * L_TOT + ii0 + np] = (uint16_t)(cord0 & (NPT - 1));
                    }
                    if (two && t == jl1) {
                        pkd[cur][np1] = make_float4(cv0.x, cv0.y, cv0.z, r2_1);
                        pkb[cur][np1] = b1;
                        sample[b1 * L_TOT + ii0 + np1] = (uint16_t)(cord0 & (NPT - 1));
                    }
                    if (a0) {
                        if (cb0 == b0 && d2f(cv0.x, cv0.y, cv0.z, p0x, p0y, p0z) <= r2_0) a0 = false;
                        if (two && cb0 == b1 && d2f(cv0.x, cv0.y, cv0.z, p1x, p1y, p1z) <= r2_1) a0 = false;
                    }
                    if (a1) {
                        if (cb1 == b0 && d2f(cv1.x, cv1.y, cv1.z, p0x, p0y, p0z) <= r2_0) a1 = false;
                        if (two && cb1 == b1 && d2f(cv1.x, cv1.y, cv1.z, p1x, p1y, p1z) <= r2_1) a1 = false;
                    }
                    np += two ? 2 : 1;
                    am = __ballot(a0 ? 1 : 0);
                }
            }
            {
                unsigned long long am = __ballot(a1 ? 1 : 0);
                while (am) {
                    const int jl0 = (int)__builtin_ctzll(am);
                    const unsigned long long am2 = am & (am - 1);
                    const bool has2 = (am2 != 0ull);
                    const int jl1 = has2 ? (int)__builtin_ctzll(am2) : jl0;
                    const float p0x = rlf(cv1.x, jl0), p0y = rlf(cv1.y, jl0), p0z = rlf(cv1.z, jl0);
                    const int   b0  = rli(cord1, jl0) >> 13;
                    const float p1x = rlf(cv1.x, jl1), p1y = rlf(cv1.y, jl1), p1z = rlf(cv1.z, jl1);
                    const int   b1  = rli(cord1, jl1) >> 13;
                    const float r2_0 = rlf((np & 64) ? cr1 : cr0, np & 63);
                    const int np1 = np + 1;
                    const float r2_1 = rlf((np1 & 64) ? cr1 : cr0, np1 & 63);
                    const bool kb = (b0 == b1) &&
                                    (d2f(p1x, p1y, p1z, p0x, p0y, p0z) <= r2_0);
                    const bool two = has2 && !kb;
                    if (t == jl0) {
                        pkd[cur][np] = make_float4(cv1.x, cv1.y, cv1.z, r2_0);
                        pkb[cur][np] = b0;
                        sample[b0 * L_TOT + ii0 + np] = (uint16_t)(cord1 & (NPT - 1));
                    }
                    if (two && t == jl1) {
                        pkd[cur][np1] = make_float4(cv1.x, cv1.y, cv1.z, r2_1);
                        pkb[cur][np1] = b1;
                        sample[b1 * L_TOT + ii0 + np1] = (uint16_t)(cord1 & (NPT - 1));
                    }
                    if (a1) {
                        if (cb1 == b0 && d2f(cv1.x, cv1.y, cv1.z, p0x, p0y, p0z) <= r2_0) a1 = false;
                        if (two && cb1 == b1 && d2f(cv1.x, cv1.y, cv1.z, p1x, p1y, p1z) <= r2_1) a1 = false;
                    }
                    np += two ? 2 : 1;
                    am = __ballot(a1 ? 1 : 0);
                }
            }
            ii = ii0 + np;
            if (t == 0) pkn[cur] = np;
            cv0 = nv0; cv1 = nv1; cord0 = nord0; cord1 = nord1;
        } else {
            // ---- waves 1..15: apply batch ph-1 via LDS quantized scan ----
            const int np = pkn[prv];
            if (np > 0) {
                const int tid = t - 64;                  // 0..959
                const int ntask = np * 216;              // 27 cells x 8-way split
                for (int task = tid; task < ntask; task += 960) {
                    int sub = task & 7;
                    int pc = task >> 3;
                    int p = pc / 27;
                    int c = pc - p * 27;
                    float4 pv = pkd[prv][p];
                    int pb_ = pkb[prv][p];
                    float r2 = pv.w;
                    int cx = cellco(pv.x) + (c % 3) - 1;
                    int cy = cellco(pv.y) + ((c / 3) % 3) - 1;
                    int cz = cellco(pv.z) + (c / 9) - 1;
                    if ((unsigned)cx > 15u || (unsigned)cy > 15u || (unsigned)cz > 15u) continue;
                    // conservative cell-box cull (margin >> any rounding diff)
                    float lox = -6.4f + 0.8f * cx, hix = lox + 0.8f;
                    float loy = -6.4f + 0.8f * cy, hiy = loy + 0.8f;
                    float loz = -6.4f + 0.8f * cz, hiz = loz + 0.8f;
                    if (cx == 0) lox = -1e30f;  if (cx == 15) hix = 1e30f;
                    if (cy == 0) loy = -1e30f;  if (cy == 15) hiy = 1e30f;
                    if (cz == 0) loz = -1e30f;  if (cz == 15) hiz = 1e30f;
                    float bdx = fmaxf(fmaxf(lox - pv.x, pv.x - hix), 0.0f);
                    float bdy = fmaxf(fmaxf(loy - pv.y, pv.y - hiy), 0.0f);
                    float bdz = fmaxf(fmaxf(loz - pv.z, pv.z - hiz), 0.0f);
                    if (bdx * bdx + bdy * bdy + bdz * bdz > r2 + 0.02f) continue;
                    int cl = (pb_ << 12) | (cz << 8) | (cy << 4) | cx;
                    int st = (int)cs16[cl];
                    int en = (int)cs16[cl + 1];
                    // scaled pick coords / thresholds (quantized domain)
                    float psx = (pv.x + 8.0f) * 4096.0f;
                    float psy = (pv.y + 8.0f) * 4096.0f;
                    float psz = (pv.z + 8.0f) * 4096.0f;
                    float thr_hi = (r2 + 0.02f) * 16777216.0f;
                    float thr_lo = (r2 - 0.02f) * 16777216.0f;
                    for (int k = st + sub; k < en; k += 8) {
                        uint64_t e = qpack[k];           // ds_read_b64
                        uint32_t lo = (uint32_t)e, hi = (uint32_t)(e >> 32);
                        float ddx = (float)(lo & 0xffffu) - psx;
                        float ddy = (float)(lo >> 16) - psy;
                        float ddz = (float)(hi & 0xffffu) - psz;
                        float d2s = ddx * ddx + ddy * ddy + ddz * ddz;
                        if (d2s <= thr_hi) {
                            if (alive2[k >> 5] & (1u << (k & 31))) {
                                bool sup = (d2s <= thr_lo);
                                if (!sup) {              // borderline: exact check
                                    float4 q = cellxyz[k];
                                    sup = d2f(q.x, q.y, q.z, pv.x, pv.y, pv.z) <= r2;
                                }
                                if (sup) {
                                    uint32_t pos = hi >> 16;
                                    atomicAnd(&alive2[k >> 5], ~(1u << (k & 31)));
                                    atomicAnd(&rem[pos >> 5], ~(1u << (pos & 31)));
                                }
                            }
                        }
                    }
                }
            }
        }
        __syncthreads();
    }
}

// ---------------- k4: write outputs ----------------
__global__ void k4_out(const float* __restrict__ xyz, const uint16_t* __restrict__ sample,
                       float* __restrict__ out) {
    int s = blockIdx.x * blockDim.x + threadIdx.x;
    if (s >= 2 * L_TOT) return;
    int idx = (int)sample[s];
    int b = s >> 14;
    const float* src = xyz + ((size_t)(b * NPT + idx)) * 3;
    float* dst = out + (size_t)s * 3;
    dst[0] = src[0]; dst[1] = src[1]; dst[2] = src[2];
    out[3 * 2 * L_TOT + s] = (float)idx;   // sample_idx as float32 values
}

extern "C" void kernel_launch(void* const* d_in, const int* in_sizes, int n_in,
                              void* d_out, int out_size, void* d_ws, size_t ws_size,
                              hipStream_t stream) {
    const float* xyz = (const float*)d_in[0];
    const float* cls = (const float*)d_in[1];
    float* out = (float*)d_out;
    char* ws = (char*)d_ws;
    // layout:
    float4*   spts    = (float4*)  (ws + 0);        // 262144
    uint32_t* slab2   = (uint32_t*)(ws + 262144);   // 4096 (2-bit labels by rank)
    uint16_t* sorder  = (uint16_t*)(ws + 278528);   // 32768
    int*      cellcnt = (int*)     (ws + 311296);   // 32768 (reused as fill counters)
    int*      cellst  = (int*)     (ws + 344064);   // 36864 (8193 ints + pad)
    float4*   cellxyz = (float4*)  (ws + 380928);   // 262144
    uint64_t* keys    = (uint64_t*)(ws + 380928);   // alias: dead after k2
    uint8_t*  umeta   = (uint8_t*) (ws + 512000);   // alias: dead after k2
    uint16_t* sample  = (uint16_t*)(ws + 643072);   // 65536

    k1_keys   <<<64,  256, 0, stream>>>(cls, keys, umeta, sample, cellcnt, slab2);
    k2_sort   <<<512, 256, 0, stream>>>(keys, umeta, xyz, spts, slab2, sorder, cellcnt);
    g2_scan   <<<1,   256, 0, stream>>>(cellcnt, cellst);
    g3_scatter<<<64,  256, 0, stream>>>(spts, cellst, cellcnt, cellxyz);
    k3_greedy <<<1,  1024, 0, stream>>>(spts, slab2, sorder, cellst, cellxyz, sample);
    k4_out    <<<128, 256, 0, stream>>>(xyz, sample, out);
}